// Round 10
// baseline (204.401 us; speedup 1.0000x reference)
//
#include <hip/hip_runtime.h>
#include <math.h>

// Capsule dynamic routing v11 — G=2 W-reuse with REGISTER priors + v9 routing.
// R9 arithmetic: G=1 has a hard ~38us floor (5.9MB W/CU through L1). G=2
// halves it. R7's G=2 failed on DS-pipe cost (LDS P + 3-round reductions);
// v9's fused routing (no max pass, Z folded, 1 reduction round) removed that.
// P[2][9][4]=72 regs + ~45 working ≈ 110-125 peak, under the measured
// 128-VGPR allocator grant at min_waves=1. Each W float4 feeds 8 FMAs.
//
// x: [B=256, R=1152, I=8] f32
// W: [C=10, R=1152, I=8, O=16] f32
// out: [B=256, C=10, O=16] f32
//
// One block per (c, b-pair). 512 threads = 128 groups of 4 lanes; 8 waves.
// Group g owns rows r = g + j*128 (j=0..8); lane q=t&3 owns o-quad.

#define C_CAPS 10
#define B_SZ   256
#define R_SZ   1152
#define I_SZ   8
#define O_SZ   16
#define G_B    2         // batches per block
#define T_THREADS 512
#define NGROUP 128       // T/4 groups
#define RPT 9            // rows per group = R / NGROUP
#define NW 8             // waves per block

__global__ __launch_bounds__(T_THREADS, 1) void capsule_kernel(
    const float* __restrict__ x,
    const float* __restrict__ w,
    float* __restrict__ out)
{
    const int c  = blockIdx.x >> 7;        // / (B/G)
    const int bb = blockIdx.x & 127;       // % (B/G)
    const int b0 = bb * G_B;
    const int t = (int)threadIdx.x;
    const int lane = t & 63;
    const int wid = t >> 6;
    const int q = t & 3;                   // o-quad index
    const int g = t >> 2;                  // group id 0..127

    __shared__ float4 red_s[NW][G_B][4];   // per-wave s-partials
    __shared__ float  red_z[NW][G_B];      // per-wave Z-partials
    __shared__ float4 s_fin[G_B][4];       // combined s per (gb,q)
    __shared__ float  z_fin[G_B];          // combined Z per gb

    // ---- priors: P[gb][j][k] = priors[b0+gb][r = g + j*128][o = q*4+k] ----
    float P[G_B][RPT][4];
    #pragma unroll
    for (int j = 0; j < RPT; ++j) {
        const int r = g + j * NGROUP;
        const float* xp = x + ((size_t)b0 * R_SZ + r) * I_SZ;
        const float4 x0a = *(const float4*)(xp);
        const float4 x0b = *(const float4*)(xp + 4);
        const float4 x1a = *(const float4*)(xp + (size_t)R_SZ * I_SZ);
        const float4 x1b = *(const float4*)(xp + (size_t)R_SZ * I_SZ + 4);
        const float xi0[I_SZ] = {x0a.x, x0a.y, x0a.z, x0a.w, x0b.x, x0b.y, x0b.z, x0b.w};
        const float xi1[I_SZ] = {x1a.x, x1a.y, x1a.z, x1a.w, x1b.x, x1b.y, x1b.z, x1b.w};

        const float* wr = w + ((size_t)c * R_SZ + r) * (I_SZ * O_SZ) + q * 4;
        float a00 = 0.f, a01 = 0.f, a02 = 0.f, a03 = 0.f;
        float a10 = 0.f, a11 = 0.f, a12 = 0.f, a13 = 0.f;
        #pragma unroll
        for (int i = 0; i < I_SZ; ++i) {
            const float4 wv = *(const float4*)(wr + i * O_SZ);   // feeds 8 FMAs
            a00 = fmaf(xi0[i], wv.x, a00);
            a01 = fmaf(xi0[i], wv.y, a01);
            a02 = fmaf(xi0[i], wv.z, a02);
            a03 = fmaf(xi0[i], wv.w, a03);
            a10 = fmaf(xi1[i], wv.x, a10);
            a11 = fmaf(xi1[i], wv.y, a11);
            a12 = fmaf(xi1[i], wv.z, a12);
            a13 = fmaf(xi1[i], wv.w, a13);
        }
        P[0][j][0] = a00; P[0][j][1] = a01; P[0][j][2] = a02; P[0][j][3] = a03;
        P[1][j][0] = a10; P[1][j][1] = a11; P[1][j][2] = a12; P[1][j][3] = a13;
    }

    float logit[G_B][RPT];
    #pragma unroll
    for (int gb = 0; gb < G_B; ++gb)
        #pragma unroll
        for (int j = 0; j < RPT; ++j) logit[gb][j] = 0.0f;

    float vq[G_B][4];

    for (int it = 0; it < 3; ++it) {
        // ---- fused exp + weighted-sum partials (no max pass; |logit|<=~40
        //      keeps exp and Z safely inside f32 range) ----
        #pragma unroll
        for (int gb = 0; gb < G_B; ++gb) {
            float sa0 = 0.f, sa1 = 0.f, sa2 = 0.f, sa3 = 0.f, zp = 0.f;
            #pragma unroll
            for (int j = 0; j < RPT; ++j) {
                const float e = __expf(logit[gb][j]);   // it==0: exp(0)=1
                zp += e;
                sa0 = fmaf(e, P[gb][j][0], sa0);
                sa1 = fmaf(e, P[gb][j][1], sa1);
                sa2 = fmaf(e, P[gb][j][2], sa2);
                sa3 = fmaf(e, P[gb][j][3], sa3);
            }
            #pragma unroll
            for (int m = 4; m <= 32; m <<= 1) {
                sa0 += __shfl_xor(sa0, m, 64);
                sa1 += __shfl_xor(sa1, m, 64);
                sa2 += __shfl_xor(sa2, m, 64);
                sa3 += __shfl_xor(sa3, m, 64);
                zp  += __shfl_xor(zp,  m, 64);
            }
            if (lane < 4) red_s[wid][gb][lane] = make_float4(sa0, sa1, sa2, sa3);
            if (lane == 0) red_z[wid][gb] = zp;
        }
        __syncthreads();

        // ---- one-wave combine (threads 0..9), then broadcast ----
        if (t < G_B * 4) {                       // t=0..7: gb=t>>2, q=t&3
            float4 a = red_s[0][t >> 2][t & 3];
            #pragma unroll
            for (int ww = 1; ww < NW; ++ww) {
                const float4 rr = red_s[ww][t >> 2][t & 3];
                a.x += rr.x; a.y += rr.y; a.z += rr.z; a.w += rr.w;
            }
            s_fin[t >> 2][t & 3] = a;
        }
        if (t >= 8 && t < 8 + G_B) {             // t=8,9: gb=t-8
            float zz = red_z[0][t - 8];
            #pragma unroll
            for (int ww = 1; ww < NW; ++ww) zz += red_z[ww][t - 8];
            z_fin[t - 8] = zz;
        }
        __syncthreads();

        // ---- normalize + squash (normalize BEFORE squaring: overflow-safe) ----
        #pragma unroll
        for (int gb = 0; gb < G_B; ++gb) {
            const float invZ = 1.0f / z_fin[gb];
            const float4 sf = s_fin[gb][q];
            const float u0 = sf.x * invZ, u1 = sf.y * invZ,
                        u2 = sf.z * invZ, u3 = sf.w * invZ;
            float nq = u0*u0 + u1*u1 + u2*u2 + u3*u3;
            nq += __shfl_xor(nq, 1, 64);
            nq += __shfl_xor(nq, 2, 64);
            const float scale = nq / ((1.0f + nq) * sqrtf(nq));
            vq[gb][0] = scale * u0; vq[gb][1] = scale * u1;
            vq[gb][2] = scale * u2; vq[gb][3] = scale * u3;
        }

        // ---- logit update (iters 0,1): logit[r] += P[r]·v ----
        if (it < 2) {
            #pragma unroll
            for (int gb = 0; gb < G_B; ++gb) {
                #pragma unroll
                for (int j = 0; j < RPT; ++j) {
                    float d = P[gb][j][0]*vq[gb][0] + P[gb][j][1]*vq[gb][1]
                            + P[gb][j][2]*vq[gb][2] + P[gb][j][3]*vq[gb][3];
                    d += __shfl_xor(d, 1, 64);
                    d += __shfl_xor(d, 2, 64);
                    logit[gb][j] += d;
                }
            }
        }
        // no end-of-iter barrier needed: red_s/red_z(it+1) writes can't race
        // s_fin(it) readers (all threads must pass barrier #1(it+1) first,
        // which is after every s_fin read completes). Same proof as v9.
    }

    // ---- write out[b0+gb, c, :]: threads 0..3 hold quads 0..3 ----
    if (t < 4) {
        #pragma unroll
        for (int gb = 0; gb < G_B; ++gb) {
            float* op = out + ((size_t)(b0 + gb) * C_CAPS + c) * O_SZ + q * 4;
            *(float4*)op = make_float4(vq[gb][0], vq[gb][1], vq[gb][2], vq[gb][3]);
        }
    }
}

extern "C" void kernel_launch(void* const* d_in, const int* in_sizes, int n_in,
                              void* d_out, int out_size, void* d_ws, size_t ws_size,
                              hipStream_t stream) {
    const float* x = (const float*)d_in[0];
    const float* w = (const float*)d_in[1];
    float* out = (float*)d_out;
    dim3 grid(C_CAPS * (B_SZ / G_B));
    dim3 block(T_THREADS);
    hipLaunchKernelGGL(capsule_kernel, grid, block, 0, stream, x, w, out);
}

// Round 11
// 83.300 us; speedup vs baseline: 2.4538x; 2.4538x over previous
//
#include <hip/hip_runtime.h>
#include <math.h>

// Capsule dynamic routing v12 — G=2 via 8-LANE GROUPS (wave-level W sharing).
// R10 lesson: allocator grants at most 128 VGPRs here; register-G=2 at
// 4-lane granularity (72 P + ~70 working) spills. v12 keeps v9's per-thread
// state EXACTLY (P[12][4]=48, ~52-60 VGPR, proven no-spill in R8/R9) and
// gets G=2 from the lane mapping instead: 8-lane groups, lanes 0-3 = batch
// b0's o-quads, lanes 4-7 = batch b1's. Both lane-sets read the SAME W
// addresses -> coalescer merges -> per-CU W stream from L2 halves
// (737 MB total vs 1.47 GB; L1-stream floor ~38us -> ~19us).
// Routing: v9 fused form (no max pass, Z folded, one reduction round;
// group-reduce masks are now 8/16/32 - one step fewer).
//
// x: [B=256, R=1152, I=8] f32
// W: [C=10, R=1152, I=8, O=16] f32
// out: [B=256, C=10, O=16] f32
//
// One block per (c, b-pair). 768 threads = 96 groups of 8 lanes; 12 waves.
// Group g owns rows r = g + j*96 (j=0..11).

#define C_CAPS 10
#define B_SZ   256
#define R_SZ   1152
#define I_SZ   8
#define O_SZ   16
#define G_B    2         // batches per block (via lane split)
#define T_THREADS 768
#define NGROUP 96        // T/8 groups
#define RPT 12           // rows per group = R / NGROUP
#define NW 12            // waves per block

__global__ __launch_bounds__(T_THREADS, 1) void capsule_kernel(
    const float* __restrict__ x,
    const float* __restrict__ w,
    float* __restrict__ out)
{
    const int c  = blockIdx.x >> 7;        // / (B/G)
    const int bb = blockIdx.x & 127;       // % (B/G)
    const int b0 = bb * G_B;
    const int t = (int)threadIdx.x;
    const int lane = t & 63;
    const int wid = t >> 6;
    const int q    = t & 3;                // o-quad index
    const int bsel = (t >> 2) & 1;         // which batch this lane serves
    const int g    = t >> 3;               // group id 0..95

    __shared__ float4 red_s[NW][G_B][4];   // per-wave s-partials
    __shared__ float  red_z[NW][G_B];      // per-wave Z-partials
    __shared__ float4 s_fin[G_B][4];       // combined s per (bsel,q)
    __shared__ float  z_fin[G_B];          // combined Z per bsel

    // ---- priors: P[j][k] = priors[b0+bsel][r = g + j*96][o = q*4+k] ----
    float P[RPT][4];
    #pragma unroll
    for (int j = 0; j < RPT; ++j) {
        const int r = g + j * NGROUP;
        const float* xp = x + ((size_t)(b0 + bsel) * R_SZ + r) * I_SZ;
        const float4 xv0 = *(const float4*)(xp);
        const float4 xv1 = *(const float4*)(xp + 4);
        const float xi[I_SZ] = {xv0.x, xv0.y, xv0.z, xv0.w,
                                xv1.x, xv1.y, xv1.z, xv1.w};
        // lanes q and q+4 read the SAME W float4 -> one transaction, two users
        const float* wr = w + ((size_t)c * R_SZ + r) * (I_SZ * O_SZ) + q * 4;
        float a0 = 0.f, a1 = 0.f, a2 = 0.f, a3 = 0.f;
        #pragma unroll
        for (int i = 0; i < I_SZ; ++i) {
            const float4 wv = *(const float4*)(wr + i * O_SZ);
            a0 = fmaf(xi[i], wv.x, a0);
            a1 = fmaf(xi[i], wv.y, a1);
            a2 = fmaf(xi[i], wv.z, a2);
            a3 = fmaf(xi[i], wv.w, a3);
        }
        P[j][0] = a0; P[j][1] = a1; P[j][2] = a2; P[j][3] = a3;
    }

    float logit[RPT];
    #pragma unroll
    for (int j = 0; j < RPT; ++j) logit[j] = 0.0f;

    float vq[4];   // this lane's o-quad of its batch's squashed output

    for (int it = 0; it < 3; ++it) {
        // ---- fused exp + weighted-sum partials (no max pass; |logit|<=~40
        //      keeps exp and Z inside f32 range) ----
        float sa0 = 0.f, sa1 = 0.f, sa2 = 0.f, sa3 = 0.f, zp = 0.f;
        #pragma unroll
        for (int j = 0; j < RPT; ++j) {
            const float e = __expf(logit[j]);   // it==0: exp(0)=1 exactly
            zp += e;
            sa0 = fmaf(e, P[j][0], sa0);
            sa1 = fmaf(e, P[j][1], sa1);
            sa2 = fmaf(e, P[j][2], sa2);
            sa3 = fmaf(e, P[j][3], sa3);
        }
        // reduce across the wave's 8 groups (lanes with equal t&7): 3 steps
        #pragma unroll
        for (int m = 8; m <= 32; m <<= 1) {
            sa0 += __shfl_xor(sa0, m, 64);
            sa1 += __shfl_xor(sa1, m, 64);
            sa2 += __shfl_xor(sa2, m, 64);
            sa3 += __shfl_xor(sa3, m, 64);
            zp  += __shfl_xor(zp,  m, 64);
        }
        if (lane < 8) {
            red_s[wid][lane >> 2][lane & 3] = make_float4(sa0, sa1, sa2, sa3);
            if ((lane & 3) == 0) red_z[wid][lane >> 2] = zp;
        }
        __syncthreads();

        // ---- one-wave combine (threads 0..9), then broadcast ----
        if (t < G_B * 4) {                       // t=0..7: bsel=t>>2, q=t&3
            float4 a = red_s[0][t >> 2][t & 3];
            #pragma unroll
            for (int ww = 1; ww < NW; ++ww) {
                const float4 rr = red_s[ww][t >> 2][t & 3];
                a.x += rr.x; a.y += rr.y; a.z += rr.z; a.w += rr.w;
            }
            s_fin[t >> 2][t & 3] = a;
        }
        if (t >= 8 && t < 8 + G_B) {             // t=8,9: bsel=t-8
            float zz = red_z[0][t - 8];
            #pragma unroll
            for (int ww = 1; ww < NW; ++ww) zz += red_z[ww][t - 8];
            z_fin[t - 8] = zz;
        }
        __syncthreads();

        // ---- normalize + squash (normalize BEFORE squaring: overflow-safe) ----
        const float invZ = 1.0f / z_fin[bsel];
        const float4 sf = s_fin[bsel][q];
        const float u0 = sf.x * invZ, u1 = sf.y * invZ,
                    u2 = sf.z * invZ, u3 = sf.w * invZ;
        float nq = u0*u0 + u1*u1 + u2*u2 + u3*u3;
        nq += __shfl_xor(nq, 1, 64);             // masks 1,2 stay within bsel
        nq += __shfl_xor(nq, 2, 64);
        const float scale = nq / ((1.0f + nq) * sqrtf(nq));
        vq[0] = scale * u0; vq[1] = scale * u1;
        vq[2] = scale * u2; vq[3] = scale * u3;

        // ---- logit update (iters 0,1): logit[r] += P[r]·v ----
        if (it < 2) {
            #pragma unroll
            for (int j = 0; j < RPT; ++j) {
                float d = P[j][0]*vq[0] + P[j][1]*vq[1]
                        + P[j][2]*vq[2] + P[j][3]*vq[3];
                d += __shfl_xor(d, 1, 64);
                d += __shfl_xor(d, 2, 64);
                logit[j] += d;
            }
        }
        // no end-of-iter barrier: red_s(it+1) writes occur only after
        // barrier #2(it) releases (all readers done); s_fin(it+1) writes
        // only after barrier #1(it+1) (all s_fin(it) reads done).
    }

    // ---- write out[b0+bsel, c, :]: threads 0..7 hold (bsel, quad) ----
    if (t < 8) {
        float* op = out + ((size_t)(b0 + (t >> 2)) * C_CAPS + c) * O_SZ + (t & 3) * 4;
        *(float4*)op = make_float4(vq[0], vq[1], vq[2], vq[3]);
    }
}

extern "C" void kernel_launch(void* const* d_in, const int* in_sizes, int n_in,
                              void* d_out, int out_size, void* d_ws, size_t ws_size,
                              hipStream_t stream) {
    const float* x = (const float*)d_in[0];
    const float* w = (const float*)d_in[1];
    float* out = (float*)d_out;
    dim3 grid(C_CAPS * (B_SZ / G_B));
    dim3 block(T_THREADS);
    hipLaunchKernelGGL(capsule_kernel, grid, block, 0, stream, x, w, out);
}